// Round 1
// baseline (276.378 us; speedup 1.0000x reference)
//
#include <hip/hip_runtime.h>

#define EPSV 1e-5f
constexpr int Bb = 4, Cc = 64, Nn = 40960, Kk = 16, Dd = 128;

typedef float f32x4 __attribute__((ext_vector_type(4)));
typedef __bf16 bf16x8 __attribute__((ext_vector_type(8)));
typedef unsigned short us8 __attribute__((ext_vector_type(8)));

__device__ inline unsigned short f2bf(float x) {
    unsigned u = __builtin_bit_cast(unsigned, x);
    u += 0x7FFFu + ((u >> 16) & 1u);   // RNE
    return (unsigned short)(u >> 16);
}

__device__ inline bf16x8 cvt8(const float* p) {
    us8 r;
#pragma unroll
    for (int i = 0; i < 8; ++i) r[i] = f2bf(p[i]);
    return __builtin_bit_cast(bf16x8, r);
}

// Pass 1: feature (B,C,N) fp32 -> ft (B,N,C) bf16.  4 threads per (b,n) row,
// each handles 16 channels.  Reads coalesced across lanes (per-instruction:
// 4 x 64B segments); writes 32 B/lane contiguous.
__global__ __launch_bounds__(256) void transpose_cvt(const float* __restrict__ f,
                                                     unsigned short* __restrict__ ft) {
    int g = blockIdx.x * 256 + threadIdx.x;   // B*N*4 threads
    int cq = g & 3;
    int bn = g >> 2;                          // b*Nn + n
    const float* src = f + (size_t)(bn / Nn) * Cc * Nn + (bn % Nn) + (size_t)cq * 16 * Nn;
    float t[16];
#pragma unroll
    for (int i = 0; i < 16; ++i) t[i] = src[(size_t)i * Nn];
    us8 o0, o1;
#pragma unroll
    for (int i = 0; i < 8; ++i) { o0[i] = f2bf(t[i]); o1[i] = f2bf(t[8 + i]); }
    unsigned short* dst = ft + (size_t)bn * 64 + cq * 16;
    *(us8*)dst = o0;
    *(us8*)(dst + 8) = o1;
}

// Main fused kernel: 16 points per workgroup, 256 threads (4 waves).
// LDS rows padded to 72 bf16 (144 B) => conflict-free ds_read_b128.
__global__ __launch_bounds__(256) void fused_main(
    const unsigned short* __restrict__ ft, const int* __restrict__ idx,
    const float* __restrict__ w1, const float* __restrict__ w2, const float* __restrict__ w3,
    const float* __restrict__ g1, const float* __restrict__ b1, const float* __restrict__ m1, const float* __restrict__ v1,
    const float* __restrict__ g2, const float* __restrict__ b2, const float* __restrict__ m2, const float* __restrict__ v2,
    const float* __restrict__ g3, const float* __restrict__ b3, const float* __restrict__ m3, const float* __restrict__ v3,
    float* __restrict__ out)
{
    __shared__ __attribute__((aligned(16))) unsigned short s_gath[256 * 72]; // 16 pts x 16 nbrs
    __shared__ __attribute__((aligned(16))) unsigned short s_h1[16 * 72];    // h1-sum, bf16
    __shared__ __attribute__((aligned(16))) unsigned short s_fo[16 * 72];    // own feature
    __shared__ __attribute__((aligned(16))) float s_out[16 * 132];           // out staging

    const int tid  = threadIdx.x;
    const int wave = tid >> 6;
    const int lane = tid & 63;
    const int c15  = lane & 15;
    const int q    = lane >> 4;

    const int wg = blockIdx.x;
    const int b  = wg / (Nn / 16);
    const int n0 = (wg - b * (Nn / 16)) * 16;

    // ---- per-lane constants (weights as register-resident B-fragments) ----
    const int o1i = wave * 16 + c15;                       // GEMM1 out channel
    const float sc1 = g1[o1i] * rsqrtf(v1[o1i] + EPSV);
    const float sh1 = b1[o1i] - m1[o1i] * sc1;
    bf16x8 bw1[2];
#pragma unroll
    for (int ks = 0; ks < 2; ++ks) bw1[ks] = cvt8(w1 + o1i * 64 + ks * 32 + q * 8);

    float sc2[2], sh2[2], sc3[2], sh3[2];
    bf16x8 bw2[2][2], bw3[2][2];
#pragma unroll
    for (int nt = 0; nt < 2; ++nt) {
        const int d = wave * 32 + nt * 16 + c15;
        sc2[nt] = g2[d] * rsqrtf(v2[d] + EPSV);
        sh2[nt] = b2[d] - m2[d] * sc2[nt];
        sc3[nt] = g3[d] * rsqrtf(v3[d] + EPSV);
        sh3[nt] = b3[d] - m3[d] * sc3[nt];
#pragma unroll
        for (int ks = 0; ks < 2; ++ks) {
            bw2[nt][ks] = cvt8(w2 + d * 64 + ks * 32 + q * 8);
            bw3[nt][ks] = cvt8(w3 + d * 64 + ks * 32 + q * 8);
        }
    }

    // ---- gather: 256 neighbor rows (128 B each), 8 lanes cooperate per row ----
#pragma unroll
    for (int it = 0; it < 8; ++it) {
        const int r   = it * 32 + (tid >> 3);      // 0..255
        const int sub = tid & 7;
        const int p = r >> 4, k = r & 15;
        const int nb = idx[((size_t)b * Nn + (n0 + p)) * Kk + k];
        const uint4 v = *(const uint4*)(ft + ((size_t)b * Nn + nb) * 64 + sub * 8);
        *(uint4*)(s_gath + r * 72 + sub * 8) = v;
    }
    if (tid < 128) {                               // own feature rows
        const int p = tid >> 3, sub = tid & 7;
        const uint4 v = *(const uint4*)(ft + ((size_t)b * Nn + (n0 + p)) * 64 + sub * 8);
        *(uint4*)(s_fo + p * 72 + sub * 8) = v;
    }
    __syncthreads();

    // ---- GEMM1 (w1) + BN+ReLU + sum over K; each wave owns one 16-wide o tile ----
#pragma unroll
    for (int mt = 0; mt < 16; ++mt) {              // mt == point index p
        const unsigned short* row = s_gath + (mt * 16 + c15) * 72;
        const bf16x8 a0 = __builtin_bit_cast(bf16x8, *(const uint4*)(row + q * 8));
        const bf16x8 a1 = __builtin_bit_cast(bf16x8, *(const uint4*)(row + 32 + q * 8));
        f32x4 acc = {0.f, 0.f, 0.f, 0.f};
        acc = __builtin_amdgcn_mfma_f32_16x16x32_bf16(a0, bw1[0], acc, 0, 0, 0);
        acc = __builtin_amdgcn_mfma_f32_16x16x32_bf16(a1, bw1[1], acc, 0, 0, 0);
        float s = 0.f;
#pragma unroll
        for (int r = 0; r < 4; ++r) s += fmaxf(acc[r] * sc1 + sh1, 0.f);
        s += __shfl_xor(s, 16, 64);
        s += __shfl_xor(s, 32, 64);
        if (lane < 16) s_h1[mt * 72 + wave * 16 + lane] = f2bf(s);
    }
    __syncthreads();

    // ---- GEMM2 (w2 on h1-sum) + skip GEMM (w3 on own feature), fused epilogue ----
    const unsigned short* h1row = s_h1 + c15 * 72;   // M index = point = lane&15
    const unsigned short* forow = s_fo + c15 * 72;
    const bf16x8 ah0 = __builtin_bit_cast(bf16x8, *(const uint4*)(h1row + q * 8));
    const bf16x8 ah1 = __builtin_bit_cast(bf16x8, *(const uint4*)(h1row + 32 + q * 8));
    const bf16x8 af0 = __builtin_bit_cast(bf16x8, *(const uint4*)(forow + q * 8));
    const bf16x8 af1 = __builtin_bit_cast(bf16x8, *(const uint4*)(forow + 32 + q * 8));

    f32x4 acc2[2], acc3[2];
#pragma unroll
    for (int nt = 0; nt < 2; ++nt) {
        acc2[nt] = (f32x4){0.f, 0.f, 0.f, 0.f};
        acc3[nt] = (f32x4){0.f, 0.f, 0.f, 0.f};
        acc2[nt] = __builtin_amdgcn_mfma_f32_16x16x32_bf16(ah0, bw2[nt][0], acc2[nt], 0, 0, 0);
        acc2[nt] = __builtin_amdgcn_mfma_f32_16x16x32_bf16(ah1, bw2[nt][1], acc2[nt], 0, 0, 0);
        acc3[nt] = __builtin_amdgcn_mfma_f32_16x16x32_bf16(af0, bw3[nt][0], acc3[nt], 0, 0, 0);
        acc3[nt] = __builtin_amdgcn_mfma_f32_16x16x32_bf16(af1, bw3[nt][1], acc3[nt], 0, 0, 0);
    }
#pragma unroll
    for (int nt = 0; nt < 2; ++nt) {
        const int d = wave * 32 + nt * 16 + c15;
#pragma unroll
        for (int r = 0; r < 4; ++r) {
            const int p = q * 4 + r;
            const float h2 = fmaxf(acc2[nt][r] * sc2[nt] + sh2[nt], 0.f);
            const float s3 = fmaxf(acc3[nt][r] * sc3[nt] + sh3[nt], 0.f);
            s_out[p * 132 + d] = h2 + s3;
        }
    }
    __syncthreads();

    // ---- coalesced store: 2 threads per d-row, 64 B per (d, point-half) ----
    {
        const int d = tid >> 1, half = tid & 1;
        float v[8];
#pragma unroll
        for (int i = 0; i < 8; ++i) v[i] = s_out[(half * 8 + i) * 132 + d];
        float* dst = out + ((size_t)b * Dd + d) * Nn + n0 + half * 8;
        f32x4 lo = {v[0], v[1], v[2], v[3]};
        f32x4 hi = {v[4], v[5], v[6], v[7]};
        *(f32x4*)dst = lo;
        *(f32x4*)(dst + 4) = hi;
    }
}

extern "C" void kernel_launch(void* const* d_in, const int* in_sizes, int n_in,
                              void* d_out, int out_size, void* d_ws, size_t ws_size,
                              hipStream_t stream) {
    const float* feature = (const float*)d_in[0];
    const int*   neigh   = (const int*)d_in[1];
    const float* w1 = (const float*)d_in[2];
    const float* g1 = (const float*)d_in[3];
    const float* b1 = (const float*)d_in[4];
    const float* m1 = (const float*)d_in[5];
    const float* v1 = (const float*)d_in[6];
    const float* w2 = (const float*)d_in[7];
    const float* g2 = (const float*)d_in[8];
    const float* b2 = (const float*)d_in[9];
    const float* m2 = (const float*)d_in[10];
    const float* v2 = (const float*)d_in[11];
    const float* w3 = (const float*)d_in[12];
    const float* g3 = (const float*)d_in[13];
    const float* b3 = (const float*)d_in[14];
    const float* m3 = (const float*)d_in[15];
    const float* v3 = (const float*)d_in[16];
    float* out = (float*)d_out;
    unsigned short* ft = (unsigned short*)d_ws;   // B*N*C bf16 = 20 MB

    transpose_cvt<<<(Bb * Nn * 4) / 256, 256, 0, stream>>>(feature, ft);
    fused_main<<<Bb * (Nn / 16), 256, 0, stream>>>(ft, neigh, w1, w2, w3,
                                                   g1, b1, m1, v1,
                                                   g2, b2, m2, v2,
                                                   g3, b3, m3, v3, out);
}